// Round 10
// baseline (536.029 us; speedup 1.0000x reference)
//
#include <hip/hip_runtime.h>

#define B_N 16384
#define D_K 512
#define C_N 1000
#define CP 1024
#define M_N 8
#define GAP_EPS 1e-3f
#define NT 8   // K-tiles of 64: K = 512

typedef __attribute__((ext_vector_type(8))) _Float16 f16x8;
typedef __attribute__((ext_vector_type(4))) float f32x4;

typedef const __attribute__((address_space(1))) unsigned int* gptr_t;
typedef __attribute__((address_space(3))) unsigned int* lptr_t;

__device__ __forceinline__ void gload16(const void* g, void* l) {
    __builtin_amdgcn_global_load_lds((gptr_t)g, (lptr_t)l, 16, 0, 0);
}

#define BAR()        asm volatile("s_barrier" ::: "memory")
#define WAIT_LGKM0() asm volatile("s_waitcnt lgkmcnt(0)" ::: "memory")
#define WAIT_VM4()   asm volatile("s_waitcnt vmcnt(4)" ::: "memory")
#define WAIT_VM0()   asm volatile("s_waitcnt vmcnt(0)" ::: "memory")
#define SCHEDB()     __builtin_amdgcn_sched_barrier(0)

__device__ __forceinline__ unsigned short h16(float f) {
    _Float16 h = (_Float16)f;   // v_cvt_f16_f32, RTN
    return *(unsigned short*)&h;
}

// ---------------- conversion kernels ----------------

__global__ __launch_bounds__(256) void ve_conv_x16(const float* __restrict__ x,
        unsigned short* __restrict__ xf, unsigned int* __restrict__ cnts) {
    int i = blockIdx.x * 256 + threadIdx.x;
    if (blockIdx.x == 0 && threadIdx.x < M_N) cnts[threadIdx.x] = 0u;
    float4 v = reinterpret_cast<const float4*>(x)[i];
    ushort4 h;
    h.x = h16(v.x); h.y = h16(v.y); h.z = h16(v.z); h.w = h16(v.w);
    reinterpret_cast<ushort4*>(xf)[i] = h;
}

// W [8][512][1000] fp32 -> WT16 [8][1024][512] fp16 (transposed, c-padded 0)
__global__ __launch_bounds__(256) void ve_conv_w16(const float* __restrict__ W,
        unsigned short* __restrict__ wt) {
    __shared__ float t[64][65];
    const int m = blockIdx.z, k0 = blockIdx.y * 64, c0 = blockIdx.x * 64;
    const int tid = threadIdx.x;
#pragma unroll
    for (int p = 0; p < 16; ++p) {
        int idx = p * 256 + tid;
        int kk = idx >> 6, cc = idx & 63;
        int c = c0 + cc;
        t[kk][cc] = (c < C_N) ? W[((size_t)m * D_K + k0 + kk) * C_N + c] : 0.f;
    }
    __syncthreads();
#pragma unroll
    for (int p = 0; p < 4; ++p) {
        int idx = p * 256 + tid;
        int cc = idx >> 4, kq = idx & 15;
        ushort4 h;
        h.x = h16(t[kq * 4 + 0][cc]); h.y = h16(t[kq * 4 + 1][cc]);
        h.z = h16(t[kq * 4 + 2][cc]); h.w = h16(t[kq * 4 + 3][cc]);
        size_t o = ((size_t)m * CP + c0 + cc) * D_K + k0 + kq * 4;
        *reinterpret_cast<ushort4*>(wt + o) = h;
    }
}

// --------- round-7-verified 8-phase 256x256 GEMM, BK=64, now NT=8, fp16 ---------
// LDS: Ab/Bb = [dbuf=T&1][128B rows x 256]; slot swizzle slot ^= (row&7),
// inverse pre-applied on global source (kswz=(l&7)^(l>>3)); gload dest linear.
// Staging schedule + vmcnt(4) accounting identical to round 7 (WAR-audited):
//   ph1: A(2i+1,h0)  ph2: A(2i+1,h1)
//   ph3: B(2i+2,h0)  ph4: B(2i+2,h1) + vmcnt(4)
//   ph5: A(2i+2,h0)  ph6: A(2i+2,h1)
//   ph7: B(2i+3,h0)  ph8: B(2i+3,h1) + vmcnt(4)

#define LD_A4(D, A, P) do { \
    af[0] = *reinterpret_cast<const f16x8*>((P) + (D)*32768 + ((A)*64 +  0)*128); \
    af[1] = *reinterpret_cast<const f16x8*>((P) + (D)*32768 + ((A)*64 + 16)*128); \
    af[2] = *reinterpret_cast<const f16x8*>((P) + (D)*32768 + ((A)*64 + 32)*128); \
    af[3] = *reinterpret_cast<const f16x8*>((P) + (D)*32768 + ((A)*64 + 48)*128); } while (0)

#define LD_B4(DST, D, P) do { \
    DST[0] = *reinterpret_cast<const f16x8*>((P) + (D)*32768 +    0); \
    DST[1] = *reinterpret_cast<const f16x8*>((P) + (D)*32768 + 2048); \
    DST[2] = *reinterpret_cast<const f16x8*>((P) + (D)*32768 + 4096); \
    DST[3] = *reinterpret_cast<const f16x8*>((P) + (D)*32768 + 6144); } while (0)

#define PH(AB, BR) do { \
    BAR(); WAIT_LGKM0(); SCHEDB(); \
    __builtin_amdgcn_s_setprio(1); \
    _Pragma("unroll") \
    for (int ii = 0; ii < 4; ++ii) { \
        _Pragma("unroll") \
        for (int jj = 0; jj < 4; ++jj) \
            acc[(AB) + ii][jj] = __builtin_amdgcn_mfma_f32_16x16x32_f16(af[ii], BR[jj], acc[(AB) + ii][jj], 0, 0, 0); \
    } \
    __builtin_amdgcn_s_setprio(0); \
    BAR(); } while (0)

__global__ __launch_bounds__(512, 2) void ve_gemm16b(
        const unsigned short* __restrict__ Xf, const unsigned short* __restrict__ WT,
        const float* __restrict__ bias, float4* __restrict__ part) {
    __shared__ unsigned short Ab[32768];   // 64 KB
    __shared__ unsigned short Bb[32768];   // 64 KB
    __shared__ float4 wtop[256][4];
    __shared__ float bs[256];

    const int tid = threadIdx.x;
    const int l = tid & 63, w = tid >> 6;
    const int wr = w >> 2, wc = w & 3;          // 2M x 4N waves; per-wave C = 128x64
    const int l15 = l & 15, kg = l >> 4;
    const int rt = blockIdx.x, ct = blockIdx.y, mb = blockIdx.z;
    const int r0 = rt * 256, c0 = ct * 256;

    if (tid < 256) {
        int c = c0 + tid;
        bs[tid] = (c < C_N) ? bias[mb * C_N + c] : -1e30f;
    }

    // ---- staging lane constants (inverse swizzle) ----
    const int kswz = (l & 7) ^ (l >> 3);
    const size_t laneOff = (size_t)((w * 8 + (l >> 3)) * 1024 + kswz * 16);
    const char* xfB = (const char*)Xf + (size_t)r0 * 1024 + laneOff;
    const char* wtB = (const char*)WT + (size_t)(mb * CP + c0) * 1024 + laneOff;

    auto stageA = [&](int T, int half) {
        const char* g = xfB + (T * 128 + half * 131072);
        unsigned short* d0 = Ab + ((T & 1) * 16384 + half * 8192 + tid * 8);
        gload16(g, d0);
        gload16(g + 65536, d0 + 4096);
    };
    auto stageB = [&](int T, int half) {
        const char* g = wtB + (T * 128 + half * 131072);
        unsigned short* d0 = Bb + ((T & 1) * 16384 + half * 8192 + tid * 8);
        gload16(g, d0);
        gload16(g + 65536, d0 + 4096);
    };

    // ---- fragment read base pointers (per-lane, loop-invariant) ----
    const char* aB = (const char*)Ab + wr * 16384 + l15 * 128;
    const char* vA0 = aB + ((kg       ^ (l15 & 7)) * 16);
    const char* vA1 = aB + (((4 | kg) ^ (l15 & 7)) * 16);
    const char* bB = (const char*)Bb + wc * 8192 + l15 * 128;
    const char* vB0 = bB + ((kg       ^ (l15 & 7)) * 16);
    const char* vB1 = bB + (((4 | kg) ^ (l15 & 7)) * 16);

    // ---- prologue: stage tiles 0,1 fully ----
    stageA(0, 0); stageB(0, 1); stageA(0, 1); stageB(0, 0);
    stageA(1, 0); stageB(1, 1); stageA(1, 1); stageB(1, 0);
    __syncthreads();   // vmcnt(0) + lgkm(0) + barrier

    f32x4 acc[8][4];
#pragma unroll
    for (int i = 0; i < 8; ++i)
#pragma unroll
        for (int j = 0; j < 4; ++j) acc[i][j] = (f32x4){0.f, 0.f, 0.f, 0.f};

    f16x8 af[4], b0r[4], b1r[4];

#pragma unroll 1
    for (int i = 0; i < 4; ++i) {
        // ===== tile 2i (dbuf 0), phases 1..4 =====
        LD_B4(b0r, 0, vB0);
        LD_A4(0, 0, vA0);
        if (i > 0) stageA(2 * i + 1, 0);
        PH(0, b0r);

        LD_B4(b1r, 0, vB1);
        LD_A4(0, 0, vA1);
        if (i > 0) stageA(2 * i + 1, 1);
        PH(0, b1r);

        LD_A4(0, 1, vA1);
        if (i < 3) stageB(2 * i + 2, 0);
        PH(4, b1r);

        LD_A4(0, 1, vA0);
        if (i < 3) { stageB(2 * i + 2, 1); WAIT_VM4(); }
        else       { WAIT_VM0(); }
        PH(4, b0r);

        // ===== tile 2i+1 (dbuf 1), phases 5..8 =====
        LD_B4(b0r, 1, vB0);
        LD_A4(1, 0, vA0);
        if (i < 3) stageA(2 * i + 2, 0);
        PH(0, b0r);

        LD_B4(b1r, 1, vB1);
        LD_A4(1, 0, vA1);
        if (i < 3) stageA(2 * i + 2, 1);
        PH(0, b1r);

        LD_A4(1, 1, vA1);
        if (i < 3) stageB(2 * i + 3, 0);
        PH(4, b1r);

        LD_A4(1, 1, vA0);
        if (i < 3) { stageB(2 * i + 3, 1); WAIT_VM4(); }
        else       { WAIT_VM0(); }
        PH(4, b0r);
    }

    // ---------------- epilogue: bias + per-wave top-2 over its 64 cols ----------------
    float bsv[4]; int cg[4];
#pragma unroll
    for (int j = 0; j < 4; ++j) {
        int cl = wc * 64 + j * 16 + l15;
        bsv[j] = bs[cl];
        cg[j] = c0 + cl;
    }
#pragma unroll
    for (int i = 0; i < 8; ++i) {
#pragma unroll
        for (int reg = 0; reg < 4; ++reg) {
            float v1 = acc[i][0][reg] + bsv[0]; int i1 = cg[0];
            float v2 = -1e30f; int i2 = 0x7fffffff;
#pragma unroll
            for (int j = 1; j < 4; ++j) {
                float v = acc[i][j][reg] + bsv[j]; int cc = cg[j];
                if (v > v1 || (v == v1 && cc < i1)) { v2 = v1; i2 = i1; v1 = v; i1 = cc; }
                else if (v > v2 || (v == v2 && cc < i2)) { v2 = v; i2 = cc; }
            }
#pragma unroll
            for (int mask = 1; mask < 16; mask <<= 1) {
                float ov1 = __shfl_xor(v1, mask); int oi1 = __shfl_xor(i1, mask);
                float ov2 = __shfl_xor(v2, mask); int oi2 = __shfl_xor(i2, mask);
                if (ov1 > v1 || (ov1 == v1 && oi1 < i1)) {
                    float nv2 = v1; int ni2 = i1;
                    if (ov2 > nv2 || (ov2 == nv2 && oi2 < ni2)) { nv2 = ov2; ni2 = oi2; }
                    v1 = ov1; i1 = oi1; v2 = nv2; i2 = ni2;
                } else if (ov1 > v2 || (ov1 == v2 && oi1 < i2)) { v2 = ov1; i2 = oi1; }
            }
            if (l15 == 0) {
                int row = wr * 128 + i * 16 + (l >> 4) * 4 + reg;
                wtop[row][wc] = make_float4(v1, __int_as_float(i1), v2, __int_as_float(i2));
            }
        }
    }
    __syncthreads();
    if (tid < 256) {
        float v1 = -1e30f; int i1 = 0x7fffffff;
        float v2 = -1e30f; int i2 = 0x7fffffff;
#pragma unroll
        for (int s = 0; s < 4; ++s) {
            float4 o = wtop[tid][s];
            float ov1 = o.x; int oi1 = __float_as_int(o.y);
            float ov2 = o.z; int oi2 = __float_as_int(o.w);
            if (ov1 > v1 || (ov1 == v1 && oi1 < i1)) {
                float nv2 = v1; int ni2 = i1;
                if (ov2 > nv2 || (ov2 == nv2 && oi2 < ni2)) { nv2 = ov2; ni2 = oi2; }
                v1 = ov1; i1 = oi1; v2 = nv2; i2 = ni2;
            } else if (ov1 > v2 || (ov1 == v2 && oi1 < i2)) { v2 = ov1; i2 = oi1; }
        }
        part[((size_t)mb * B_N + r0 + tid) * 4 + ct] =
            make_float4(v1, __int_as_float(i1), v2, __int_as_float(i2));
    }
}

// -------- merge 4 C-tiles, write approx argmax, flag small-gap rows per model --------

__global__ __launch_bounds__(256) void ve_flag4(const float4* __restrict__ part,
        unsigned int* __restrict__ wout, unsigned int* __restrict__ rlist,
        unsigned int* __restrict__ cnts) {
    int r = blockIdx.x * 256 + threadIdx.x;
#pragma unroll
    for (int m = 0; m < M_N; ++m) {
        float v1 = -1e30f; int i1 = 0x7fffffff;
        float v2 = -1e30f; int i2 = 0x7fffffff;
#pragma unroll
        for (int t = 0; t < 4; ++t) {
            float4 o = part[((size_t)m * B_N + r) * 4 + t];
            float ov1 = o.x; int oi1 = __float_as_int(o.y);
            float ov2 = o.z; int oi2 = __float_as_int(o.w);
            if (ov1 > v1 || (ov1 == v1 && oi1 < i1)) {
                float nv2 = v1; int ni2 = i1;
                if (ov2 > nv2 || (ov2 == nv2 && oi2 < ni2)) { nv2 = ov2; ni2 = oi2; }
                v1 = ov1; i1 = oi1; v2 = nv2; i2 = ni2;
            } else if (ov1 > v2 || (ov1 == v2 && oi1 < i2)) { v2 = ov1; i2 = oi1; }
        }
        wout[m * B_N + r] = (unsigned)i1;
        if (v1 - v2 <= GAP_EPS) {
            unsigned pos = atomicAdd(&cnts[m], 1u);
            rlist[m * B_N + pos] = (unsigned)r;
        }
    }
}

// -------- grouped exact pass (32 rows/block): fp32 serial-k FMA, numpy-matching --------

__global__ __launch_bounds__(256) void ve_exact_g(
        const float* __restrict__ x, const float* __restrict__ W,
        const float* __restrict__ bias, const unsigned int* __restrict__ rlist,
        const unsigned int* __restrict__ cnts, float2* __restrict__ part2) {
    __shared__ float xs[32][33];
    __shared__ float wsm[32][128];
    __shared__ int rg[32];
    const int ct = blockIdx.x, m = blockIdx.z;
    const int tid = threadIdx.x;
    const int tx = tid & 15, ty = tid >> 4;
    const int c0 = ct * 128;
    const unsigned nm = cnts[m];

    for (unsigned rb = blockIdx.y; rb * 32 < nm; rb += gridDim.y) {
        __syncthreads();
        if (tid < 32) {
            unsigned idx = rb * 32 + tid;
            rg[tid] = (idx < nm) ? (int)rlist[m * B_N + idx] : 0;
        }
        __syncthreads();

        float acc[2][8];
#pragma unroll
        for (int i = 0; i < 2; i++)
#pragma unroll
            for (int j = 0; j < 8; j++) acc[i][j] = 0.f;

        for (int kt = 0; kt < D_K; kt += 32) {
            {
                int row = tid >> 3, kq = tid & 7;
                float4 v = *reinterpret_cast<const float4*>(
                        x + (size_t)rg[row] * D_K + kt + kq * 4);
                int kk = kq * 4;
                xs[kk + 0][row] = v.x; xs[kk + 1][row] = v.y;
                xs[kk + 2][row] = v.z; xs[kk + 3][row] = v.w;
            }
#pragma unroll
            for (int i = 0; i < 4; i++) {
                int li = tid + i * 256;
                int kk = li >> 5, cq = li & 31;
                int c = c0 + cq * 4;
                const float* p = W + ((size_t)(m * D_K + kt + kk)) * C_N + c;
                float4 v;
                if (c + 3 < C_N) v = *reinterpret_cast<const float4*>(p);
                else {
                    v.x = (c + 0 < C_N) ? p[0] : 0.f; v.y = (c + 1 < C_N) ? p[1] : 0.f;
                    v.z = (c + 2 < C_N) ? p[2] : 0.f; v.w = (c + 3 < C_N) ? p[3] : 0.f;
                }
                wsm[kk][cq * 4 + 0] = v.x; wsm[kk][cq * 4 + 1] = v.y;
                wsm[kk][cq * 4 + 2] = v.z; wsm[kk][cq * 4 + 3] = v.w;
            }
            __syncthreads();
            for (int kk = 0; kk < 32; kk++) {
                float a0 = xs[kk][ty], a1 = xs[kk][ty + 16];
                float bb[8];
#pragma unroll
                for (int j = 0; j < 8; j++) bb[j] = wsm[kk][tx + j * 16];
#pragma unroll
                for (int j = 0; j < 8; j++) {
                    acc[0][j] += a0 * bb[j];
                    acc[1][j] += a1 * bb[j];
                }
            }
            __syncthreads();
        }

        const float NEG_INF = -__builtin_huge_valf();
        float bv[8]; int cv[8];
#pragma unroll
        for (int j = 0; j < 8; j++) {
            int c = c0 + tx + j * 16;
            cv[j] = c;
            bv[j] = (c < C_N) ? bias[m * C_N + c] : 0.f;
        }
#pragma unroll
        for (int i = 0; i < 2; i++) {
            float best = NEG_INF; int bidx = 0x7fffffff;
#pragma unroll
            for (int j = 0; j < 8; j++) {
                int c = cv[j];
                float v = (c < C_N) ? (acc[i][j] + bv[j]) : NEG_INF;
                if (v > best || (v == best && c < bidx)) { best = v; bidx = c; }
            }
#pragma unroll
            for (int mask = 1; mask < 16; mask <<= 1) {
                float ov = __shfl_xor(best, mask);
                int oi = __shfl_xor(bidx, mask);
                if (ov > best || (ov == best && oi < bidx)) { best = ov; bidx = oi; }
            }
            unsigned slot = rb * 32 + ty + i * 16;
            if (tx == 0 && slot < nm)
                part2[((size_t)m * B_N + slot) * 8 + ct] = make_float2(best, __int_as_float(bidx));
        }
    }
}

// merge exact per-ct partials -> final argmax for flagged rows
__global__ __launch_bounds__(256) void ve_merge_x(const float2* __restrict__ part2,
        const unsigned int* __restrict__ rlist, const unsigned int* __restrict__ cnts,
        unsigned int* __restrict__ wout) {
    int gid = blockIdx.x * 256 + threadIdx.x;
    int m = gid >> 14, s = gid & (B_N - 1);
    if (s < (int)cnts[m]) {
        const float NEG_INF = -__builtin_huge_valf();
        float best = NEG_INF; int bidx = 0x7fffffff;
#pragma unroll
        for (int ctt = 0; ctt < 8; ctt++) {
            float2 p = part2[((size_t)m * B_N + s) * 8 + ctt];
            int oi = __float_as_int(p.y);
            if (p.x > best || (p.x == best && oi < bidx)) { best = p.x; bidx = oi; }
        }
        wout[m * B_N + rlist[m * B_N + s]] = (unsigned)bidx;
    }
}

// -------- fused zero + weighted vote: block owns 256 rows --------
__global__ __launch_bounds__(256) void ve_votef(const unsigned int* __restrict__ wout,
        const float* __restrict__ coefs, float* __restrict__ out) {
    const int tid = threadIdx.x;
    float4* po = reinterpret_cast<float4*>(out) + (size_t)blockIdx.x * 64000;
    const float4 z = make_float4(0.f, 0.f, 0.f, 0.f);
    for (int i = 0; i < 250; ++i) po[i * 256 + tid] = z;
    __syncthreads();
    int r = blockIdx.x * 256 + tid;
#pragma unroll
    for (int m = 0; m < M_N; ++m)
        out[(size_t)r * C_N + wout[m * B_N + r]] += coefs[m] * 0.125f;
}

// ================= fallback: proven round-1 fp32 path =================

#define TM 128
#define TN 128
#define TK 32
#define CT 8

__global__ __launch_bounds__(256) void ve_zero_out(float* __restrict__ out, int n4) {
    int i = blockIdx.x * blockDim.x + threadIdx.x;
    const float4 z = make_float4(0.f, 0.f, 0.f, 0.f);
    for (; i < n4; i += gridDim.x * blockDim.x)
        reinterpret_cast<float4*>(out)[i] = z;
}

__global__ __launch_bounds__(256) void ve_gemm_argmax_fb(
        const float* __restrict__ x, const float* __restrict__ W,
        const float* __restrict__ bias, float2* __restrict__ part) {
    __shared__ float xs[TK][TM + 1];
    __shared__ float ws[TK][TN];
    const int ct = blockIdx.x, rt = blockIdx.y, m = blockIdx.z;
    const int tid = threadIdx.x;
    const int tx = tid & 15, ty = tid >> 4;
    const int r0 = rt * TM, c0 = ct * TN;
    float acc[8][8];
#pragma unroll
    for (int i = 0; i < 8; i++)
#pragma unroll
        for (int j = 0; j < 8; j++) acc[i][j] = 0.f;
    const float* xbase = x + (size_t)r0 * D_K;
    for (int kt = 0; kt < D_K; kt += TK) {
#pragma unroll
        for (int i = 0; i < 4; i++) {
            int li = tid + i * 256;
            int row = li >> 3, kq = li & 7;
            float4 v = *reinterpret_cast<const float4*>(xbase + (size_t)row * D_K + kt + kq * 4);
            int kk = kq * 4;
            xs[kk + 0][row] = v.x; xs[kk + 1][row] = v.y;
            xs[kk + 2][row] = v.z; xs[kk + 3][row] = v.w;
        }
#pragma unroll
        for (int i = 0; i < 4; i++) {
            int li = tid + i * 256;
            int kk = li >> 5, cq = li & 31;
            int c = c0 + cq * 4;
            const float* p = W + ((size_t)(m * D_K + kt + kk)) * C_N + c;
            float4 v;
            if (c + 3 < C_N) v = *reinterpret_cast<const float4*>(p);
            else {
                v.x = (c + 0 < C_N) ? p[0] : 0.f; v.y = (c + 1 < C_N) ? p[1] : 0.f;
                v.z = (c + 2 < C_N) ? p[2] : 0.f; v.w = (c + 3 < C_N) ? p[3] : 0.f;
            }
            ws[kk][cq * 4 + 0] = v.x; ws[kk][cq * 4 + 1] = v.y;
            ws[kk][cq * 4 + 2] = v.z; ws[kk][cq * 4 + 3] = v.w;
        }
        __syncthreads();
        for (int kk = 0; kk < TK; kk++) {
            float a[8], bb[8];
#pragma unroll
            for (int i = 0; i < 8; i++) a[i] = xs[kk][ty + i * 16];
#pragma unroll
            for (int j = 0; j < 8; j++) bb[j] = ws[kk][tx + j * 16];
#pragma unroll
            for (int i = 0; i < 8; i++)
#pragma unroll
                for (int j = 0; j < 8; j++) acc[i][j] += a[i] * bb[j];
        }
        __syncthreads();
    }
    const float NEG_INF = -__builtin_huge_valf();
    float bv[8]; int cv[8];
#pragma unroll
    for (int j = 0; j < 8; j++) {
        int c = c0 + tx + j * 16;
        cv[j] = c;
        bv[j] = (c < C_N) ? bias[m * C_N + c] : 0.f;
    }
#pragma unroll
    for (int i = 0; i < 8; i++) {
        int r = r0 + ty + i * 16;
        float best = NEG_INF; int bidx = 0x7fffffff;
#pragma unroll
        for (int j = 0; j < 8; j++) {
            int c = cv[j];
            float v = (c < C_N) ? (acc[i][j] + bv[j]) : NEG_INF;
            if (v > best || (v == best && c < bidx)) { best = v; bidx = c; }
        }
#pragma unroll
        for (int mask = 1; mask < 16; mask <<= 1) {
            float ov = __shfl_xor(best, mask);
            int oi = __shfl_xor(bidx, mask);
            if (ov > best || (ov == best && oi < bidx)) { best = ov; bidx = oi; }
        }
        if (tx == 0) part[((size_t)m * B_N + r) * CT + ct] = make_float2(best, __int_as_float(bidx));
    }
}

__global__ __launch_bounds__(256) void ve_vote_fb(const float2* __restrict__ part,
        const float* __restrict__ coefs, float* __restrict__ out) {
    int r = blockIdx.x * blockDim.x + threadIdx.x;
    if (r >= B_N) return;
    const float NEG_INF = -__builtin_huge_valf();
#pragma unroll
    for (int m = 0; m < M_N; m++) {
        float best = NEG_INF; int bidx = 0x7fffffff;
#pragma unroll
        for (int ctt = 0; ctt < CT; ctt++) {
            float2 p = part[((size_t)m * B_N + r) * CT + ctt];
            int oi = __float_as_int(p.y);
            if (p.x > best || (p.x == best && oi < bidx)) { best = p.x; bidx = oi; }
        }
        out[(size_t)r * C_N + bidx] += coefs[m] * 0.125f;
    }
}

// ================= launcher =================

extern "C" void kernel_launch(void* const* d_in, const int* in_sizes, int n_in,
                              void* d_out, int out_size, void* d_ws, size_t ws_size,
                              hipStream_t stream) {
    const float* x     = (const float*)d_in[0];
    const float* W     = (const float*)d_in[1];
    const float* bias  = (const float*)d_in[2];
    const float* coefs = (const float*)d_in[3];
    float* out = (float*)d_out;

    const size_t NEED = (57ull << 20) + 4096;
    if (ws_size >= NEED) {
        char* ws = (char*)d_ws;
        unsigned short* Xf    = (unsigned short*)(ws);                   // 16 MiB
        unsigned short* WT16  = (unsigned short*)(ws + (16ull << 20));   //  8 MiB
        float4*         part  = (float4*)(ws + (24ull << 20));           //  8 MiB
        float2*         part2 = (float2*)(ws + (32ull << 20));           //  8 MiB
        unsigned int*   wout  = (unsigned int*)(ws + (40ull << 20));     // 512 KiB
        unsigned int*   rlist = (unsigned int*)(ws + (40ull << 20) + (512ull << 10)); // 512 KiB
        unsigned int*   cnts  = (unsigned int*)(ws + (41ull << 20));     // 32 B

        ve_conv_x16<<<8192, 256, 0, stream>>>(x, Xf, cnts);
        ve_conv_w16<<<dim3(16, 8, 8), 256, 0, stream>>>(W, WT16);
        ve_gemm16b<<<dim3(64, 4, 8), 512, 0, stream>>>(Xf, WT16, bias, part);
        ve_flag4<<<64, 256, 0, stream>>>(part, wout, rlist, cnts);
        ve_exact_g<<<dim3(8, 16, 8), 256, 0, stream>>>(x, W, bias, rlist, cnts, part2);
        ve_merge_x<<<512, 256, 0, stream>>>(part2, rlist, cnts, wout);
        ve_votef<<<64, 256, 0, stream>>>(wout, coefs, out);
    } else {
        float2* partf = (float2*)d_ws;
        ve_zero_out<<<2048, 256, 0, stream>>>(out, B_N * C_N / 4);
        dim3 grid(CT, B_N / TM, M_N);
        ve_gemm_argmax_fb<<<grid, 256, 0, stream>>>(x, W, bias, partf);
        ve_vote_fb<<<(B_N + 255) / 256, 256, 0, stream>>>(partf, coefs, out);
    }
}

// Round 11
// 463.177 us; speedup vs baseline: 1.1573x; 1.1573x over previous
//
#include <hip/hip_runtime.h>

#define B_N 16384
#define D_K 512
#define C_N 1000
#define CP 1024
#define M_N 8
#define GAP_EPS 1e-3f

typedef __attribute__((ext_vector_type(8))) _Float16 f16x8;
typedef __attribute__((ext_vector_type(4))) float f32x4;

typedef const __attribute__((address_space(1))) unsigned int* gptr_t;
typedef __attribute__((address_space(3))) unsigned int* lptr_t;

__device__ __forceinline__ void gload16(const void* g, void* l) {
    __builtin_amdgcn_global_load_lds((gptr_t)g, (lptr_t)l, 16, 0, 0);
}

__device__ __forceinline__ unsigned short h16(float f) {
    _Float16 h = (_Float16)f;   // v_cvt_f16_f32, RTN
    return *(unsigned short*)&h;
}

// ---------------- conversion kernels ----------------

__global__ __launch_bounds__(256) void ve_conv_x16(const float* __restrict__ x,
        unsigned short* __restrict__ xf, unsigned int* __restrict__ cnts) {
    int i = blockIdx.x * 256 + threadIdx.x;
    if (blockIdx.x == 0 && threadIdx.x < M_N) cnts[threadIdx.x] = 0u;
    float4 v = reinterpret_cast<const float4*>(x)[i];
    ushort4 h;
    h.x = h16(v.x); h.y = h16(v.y); h.z = h16(v.z); h.w = h16(v.w);
    reinterpret_cast<ushort4*>(xf)[i] = h;
}

// W [8][512][1000] fp32 -> WT16 [8][1024][512] fp16 (transposed, c-padded 0)
__global__ __launch_bounds__(256) void ve_conv_w16(const float* __restrict__ W,
        unsigned short* __restrict__ wt) {
    __shared__ float t[64][65];
    const int m = blockIdx.z, k0 = blockIdx.y * 64, c0 = blockIdx.x * 64;
    const int tid = threadIdx.x;
#pragma unroll
    for (int p = 0; p < 16; ++p) {
        int idx = p * 256 + tid;
        int kk = idx >> 6, cc = idx & 63;
        int c = c0 + cc;
        t[kk][cc] = (c < C_N) ? W[((size_t)m * D_K + k0 + kk) * C_N + c] : 0.f;
    }
    __syncthreads();
#pragma unroll
    for (int p = 0; p < 4; ++p) {
        int idx = p * 256 + tid;
        int cc = idx >> 4, kq = idx & 15;
        ushort4 h;
        h.x = h16(t[kq * 4 + 0][cc]); h.y = h16(t[kq * 4 + 1][cc]);
        h.z = h16(t[kq * 4 + 2][cc]); h.w = h16(t[kq * 4 + 3][cc]);
        size_t o = ((size_t)m * CP + c0 + cc) * D_K + k0 + kq * 4;
        *reinterpret_cast<ushort4*>(wt + o) = h;
    }
}

// ------- fp16 MFMA GEMM: 128 rows x ALL 1024 cols per block (ct loop inside) -------
// K-loop + LDS layout bit-identical to the round-9-verified kernel (BK=64, two
// 32-k sub-tiles, paired-row XOR swizzle, inverse pre-applied on global src).
// Per ct: K-loop then per-lane running (v1,i1,v2) update (no butterfly).
// One butterfly + cross-wave merge at the very end. No i2: ties give gap 0 ->
// flagged -> exact fp32 pass resolves the index, so fast-path index order is
// irrelevant.

__global__ __launch_bounds__(256, 3) void ve_gemm16c(
        const unsigned short* __restrict__ Xf, const unsigned short* __restrict__ WT,
        const float* __restrict__ bias, float4* __restrict__ part) {
    __shared__ unsigned short At[8192];   // 16 KB: [subk][128 rows x 32 k]
    __shared__ unsigned short Bt[8192];   // 16 KB

    const int tid = threadIdx.x;
    const int l = tid & 63, w = tid >> 6;
    const int wr = w >> 1, wc = w & 1;        // 2x2 waves; per-wave C = 64x64 per ct
    const int l15 = l & 15, kg = l >> 4;
    const int rt = blockIdx.x, mb = blockIdx.z;
    const int r0 = rt * 128;

    // staging lane constants (round-9-verified inverse swizzle)
    const int lhi = l >> 3, llo = l & 7;
    const int s3g = llo ^ lhi;
    const int srow16 = (lhi << 1) | (s3g >> 2);
    const int kgs = (s3g & 3) * 8;            // shorts

    const unsigned short* xA0 = Xf + (size_t)(r0 +      w * 16 + srow16) * D_K + kgs;
    const unsigned short* xA1 = Xf + (size_t)(r0 + 64 + w * 16 + srow16) * D_K + kgs;
    const unsigned short* wB  = WT + (size_t)(mb * CP + w * 16 + srow16) * D_K + kgs;
    unsigned short* dA00 = At + tid * 8;
    unsigned short* dA01 = At + 2048 + tid * 8;
    unsigned short* dA10 = At + 4096 + tid * 8;
    unsigned short* dA11 = At + 6144 + tid * 8;
    unsigned short* dB00 = Bt + tid * 8;
    unsigned short* dB01 = Bt + 2048 + tid * 8;
    unsigned short* dB10 = Bt + 4096 + tid * 8;
    unsigned short* dB11 = Bt + 6144 + tid * 8;

    // fragment read pointers (loop-invariant; subk1 = +8192 bytes)
    auto ldsoff = [&](int row, int kc) {
        return (row >> 1) * 64 + (((((row & 1) << 2) | kc) ^ ((row >> 1) & 7)) * 8);
    };
    const char* aP[4]; const char* bP[4];
#pragma unroll
    for (int i = 0; i < 4; ++i) {
        aP[i] = (const char*)At + 2 * ldsoff(wr * 64 + i * 16 + l15, kg);
        bP[i] = (const char*)Bt + 2 * ldsoff(wc * 64 + i * 16 + l15, kg);
    }

    // running per-lane top-2: row = wr*64 + i*16 + (l>>4)*4 + reg
    float rv1[4][4], rv2[4][4]; int ri1[4][4];
#pragma unroll
    for (int i = 0; i < 4; ++i)
#pragma unroll
        for (int reg = 0; reg < 4; ++reg) {
            rv1[i][reg] = -1e30f; rv2[i][reg] = -1e30f; ri1[i][reg] = 0;
        }

#pragma unroll 1
    for (int ct = 0; ct < 8; ++ct) {
        const unsigned short* xB0 = wB + (size_t)(ct * 128) * D_K;
        const unsigned short* xB1 = xB0 + (size_t)64 * D_K;

        f32x4 acc[4][4];
#pragma unroll
        for (int i = 0; i < 4; ++i)
#pragma unroll
            for (int j = 0; j < 4; ++j) acc[i][j] = (f32x4){0.f, 0.f, 0.f, 0.f};

#pragma unroll
        for (int t = 0; t < 8; ++t) {
            gload16(xA0 + t * 64,      dA00);
            gload16(xA1 + t * 64,      dA01);
            gload16(xA0 + t * 64 + 32, dA10);
            gload16(xA1 + t * 64 + 32, dA11);
            gload16(xB0 + t * 64,      dB00);
            gload16(xB1 + t * 64,      dB01);
            gload16(xB0 + t * 64 + 32, dB10);
            gload16(xB1 + t * 64 + 32, dB11);
            __syncthreads();   // drains vmcnt(0): tile t fully in LDS

            f16x8 af[4], bf[4];
#pragma unroll
            for (int i = 0; i < 4; ++i) af[i] = *reinterpret_cast<const f16x8*>(aP[i]);
#pragma unroll
            for (int j = 0; j < 4; ++j) bf[j] = *reinterpret_cast<const f16x8*>(bP[j]);
#pragma unroll
            for (int i = 0; i < 4; ++i)
#pragma unroll
                for (int j = 0; j < 4; ++j)
                    acc[i][j] = __builtin_amdgcn_mfma_f32_16x16x32_f16(af[i], bf[j], acc[i][j], 0, 0, 0);
#pragma unroll
            for (int i = 0; i < 4; ++i) af[i] = *reinterpret_cast<const f16x8*>(aP[i] + 8192);
#pragma unroll
            for (int j = 0; j < 4; ++j) bf[j] = *reinterpret_cast<const f16x8*>(bP[j] + 8192);
#pragma unroll
            for (int i = 0; i < 4; ++i)
#pragma unroll
                for (int j = 0; j < 4; ++j)
                    acc[i][j] = __builtin_amdgcn_mfma_f32_16x16x32_f16(af[i], bf[j], acc[i][j], 0, 0, 0);
            __syncthreads();   // all LDS reads of tile t done before next stage
        }

        // ---- running top-2 update for this ct (registers only) ----
        float bsv[4]; int cg[4];
#pragma unroll
        for (int j = 0; j < 4; ++j) {
            int c = ct * 128 + wc * 64 + j * 16 + l15;
            cg[j] = c;
            bsv[j] = (c < C_N) ? bias[mb * C_N + c] : -1e30f;
        }
#pragma unroll
        for (int i = 0; i < 4; ++i)
#pragma unroll
            for (int reg = 0; reg < 4; ++reg) {
#pragma unroll
                for (int j = 0; j < 4; ++j) {
                    float v = acc[i][j][reg] + bsv[j];
                    float mn = fminf(v, rv1[i][reg]);
                    rv2[i][reg] = fmaxf(rv2[i][reg], mn);
                    bool gt = v > rv1[i][reg];
                    ri1[i][reg] = gt ? cg[j] : ri1[i][reg];
                    rv1[i][reg] = fmaxf(rv1[i][reg], v);
                }
            }
    }

    // ---- single butterfly over the 16 column-lanes, then cross-wc merge ----
    float4 (*wtop)[2] = reinterpret_cast<float4(*)[2]>(At);   // overlays dead At
#pragma unroll
    for (int i = 0; i < 4; ++i)
#pragma unroll
        for (int reg = 0; reg < 4; ++reg) {
            float v1 = rv1[i][reg], v2 = rv2[i][reg]; int i1 = ri1[i][reg];
#pragma unroll
            for (int mask = 1; mask < 16; mask <<= 1) {
                float ov1 = __shfl_xor(v1, mask);
                int   oi1 = __shfl_xor(i1, mask);
                float ov2 = __shfl_xor(v2, mask);
                float mn = fminf(v1, ov1);
                bool gt = ov1 > v1;
                i1 = gt ? oi1 : i1;
                v1 = fmaxf(v1, ov1);
                v2 = fmaxf(fmaxf(v2, ov2), mn);
            }
            if (l15 == 0) {
                int row = wr * 64 + i * 16 + (l >> 4) * 4 + reg;
                wtop[row][wc] = make_float4(v1, __int_as_float(i1), v2, 0.f);
            }
        }
    __syncthreads();
    if (tid < 128) {
        float4 a = wtop[tid][0], b = wtop[tid][1];
        float v1, v2; int i1;
        if (b.x > a.x) {
            v1 = b.x; i1 = __float_as_int(b.y);
            v2 = fmaxf(a.x, b.z);
        } else {
            v1 = a.x; i1 = __float_as_int(a.y);
            v2 = fmaxf(b.x, a.z);
        }
        part[(size_t)mb * B_N + r0 + tid] = make_float4(v1, __int_as_float(i1), v2, 0.f);
    }
}

// -------- write approx argmax, flag small-gap rows per model --------

__global__ __launch_bounds__(256) void ve_flagS(const float4* __restrict__ part,
        unsigned int* __restrict__ wout, unsigned int* __restrict__ rlist,
        unsigned int* __restrict__ cnts) {
    int r = blockIdx.x * 256 + threadIdx.x;
#pragma unroll
    for (int m = 0; m < M_N; ++m) {
        float4 p = part[(size_t)m * B_N + r];
        wout[m * B_N + r] = (unsigned)__float_as_int(p.y);
        if (p.x - p.z <= GAP_EPS) {
            unsigned pos = atomicAdd(&cnts[m], 1u);
            rlist[m * B_N + pos] = (unsigned)r;
        }
    }
}

// -------- grouped exact pass (32 rows/block): fp32 serial-k FMA, numpy-matching --------

__global__ __launch_bounds__(256) void ve_exact_g(
        const float* __restrict__ x, const float* __restrict__ W,
        const float* __restrict__ bias, const unsigned int* __restrict__ rlist,
        const unsigned int* __restrict__ cnts, float2* __restrict__ part2) {
    __shared__ float xs[32][33];
    __shared__ float wsm[32][128];
    __shared__ int rg[32];
    const int ct = blockIdx.x, m = blockIdx.z;
    const int tid = threadIdx.x;
    const int tx = tid & 15, ty = tid >> 4;
    const int c0 = ct * 128;
    const unsigned nm = cnts[m];

    for (unsigned rb = blockIdx.y; rb * 32 < nm; rb += gridDim.y) {
        __syncthreads();
        if (tid < 32) {
            unsigned idx = rb * 32 + tid;
            rg[tid] = (idx < nm) ? (int)rlist[m * B_N + idx] : 0;
        }
        __syncthreads();

        float acc[2][8];
#pragma unroll
        for (int i = 0; i < 2; i++)
#pragma unroll
            for (int j = 0; j < 8; j++) acc[i][j] = 0.f;

        for (int kt = 0; kt < D_K; kt += 32) {
            {
                int row = tid >> 3, kq = tid & 7;
                float4 v = *reinterpret_cast<const float4*>(
                        x + (size_t)rg[row] * D_K + kt + kq * 4);
                int kk = kq * 4;
                xs[kk + 0][row] = v.x; xs[kk + 1][row] = v.y;
                xs[kk + 2][row] = v.z; xs[kk + 3][row] = v.w;
            }
#pragma unroll
            for (int i = 0; i < 4; i++) {
                int li = tid + i * 256;
                int kk = li >> 5, cq = li & 31;
                int c = c0 + cq * 4;
                const float* p = W + ((size_t)(m * D_K + kt + kk)) * C_N + c;
                float4 v;
                if (c + 3 < C_N) v = *reinterpret_cast<const float4*>(p);
                else {
                    v.x = (c + 0 < C_N) ? p[0] : 0.f; v.y = (c + 1 < C_N) ? p[1] : 0.f;
                    v.z = (c + 2 < C_N) ? p[2] : 0.f; v.w = (c + 3 < C_N) ? p[3] : 0.f;
                }
                wsm[kk][cq * 4 + 0] = v.x; wsm[kk][cq * 4 + 1] = v.y;
                wsm[kk][cq * 4 + 2] = v.z; wsm[kk][cq * 4 + 3] = v.w;
            }
            __syncthreads();
            for (int kk = 0; kk < 32; kk++) {
                float a0 = xs[kk][ty], a1 = xs[kk][ty + 16];
                float bb[8];
#pragma unroll
                for (int j = 0; j < 8; j++) bb[j] = wsm[kk][tx + j * 16];
#pragma unroll
                for (int j = 0; j < 8; j++) {
                    acc[0][j] += a0 * bb[j];
                    acc[1][j] += a1 * bb[j];
                }
            }
            __syncthreads();
        }

        const float NEG_INF = -__builtin_huge_valf();
        float bv[8]; int cv[8];
#pragma unroll
        for (int j = 0; j < 8; j++) {
            int c = c0 + tx + j * 16;
            cv[j] = c;
            bv[j] = (c < C_N) ? bias[m * C_N + c] : 0.f;
        }
#pragma unroll
        for (int i = 0; i < 2; i++) {
            float best = NEG_INF; int bidx = 0x7fffffff;
#pragma unroll
            for (int j = 0; j < 8; j++) {
                int c = cv[j];
                float v = (c < C_N) ? (acc[i][j] + bv[j]) : NEG_INF;
                if (v > best || (v == best && c < bidx)) { best = v; bidx = c; }
            }
#pragma unroll
            for (int mask = 1; mask < 16; mask <<= 1) {
                float ov = __shfl_xor(best, mask);
                int oi = __shfl_xor(bidx, mask);
                if (ov > best || (ov == best && oi < bidx)) { best = ov; bidx = oi; }
            }
            unsigned slot = rb * 32 + ty + i * 16;
            if (tx == 0 && slot < nm)
                part2[((size_t)m * B_N + slot) * 8 + ct] = make_float2(best, __int_as_float(bidx));
        }
    }
}

// merge exact per-ct partials -> final argmax for flagged rows
__global__ __launch_bounds__(256) void ve_merge_x(const float2* __restrict__ part2,
        const unsigned int* __restrict__ rlist, const unsigned int* __restrict__ cnts,
        unsigned int* __restrict__ wout) {
    int gid = blockIdx.x * 256 + threadIdx.x;
    int m = gid >> 14, s = gid & (B_N - 1);
    if (s < (int)cnts[m]) {
        const float NEG_INF = -__builtin_huge_valf();
        float best = NEG_INF; int bidx = 0x7fffffff;
#pragma unroll
        for (int ctt = 0; ctt < 8; ctt++) {
            float2 p = part2[((size_t)m * B_N + s) * 8 + ctt];
            int oi = __float_as_int(p.y);
            if (p.x > best || (p.x == best && oi < bidx)) { best = p.x; bidx = oi; }
        }
        wout[m * B_N + rlist[m * B_N + s]] = (unsigned)bidx;
    }
}

// -------- fused zero + weighted vote: block owns 256 rows --------
__global__ __launch_bounds__(256) void ve_votef(const unsigned int* __restrict__ wout,
        const float* __restrict__ coefs, float* __restrict__ out) {
    const int tid = threadIdx.x;
    float4* po = reinterpret_cast<float4*>(out) + (size_t)blockIdx.x * 64000;
    const float4 z = make_float4(0.f, 0.f, 0.f, 0.f);
    for (int i = 0; i < 250; ++i) po[i * 256 + tid] = z;
    __syncthreads();
    int r = blockIdx.x * 256 + tid;
#pragma unroll
    for (int m = 0; m < M_N; ++m)
        out[(size_t)r * C_N + wout[m * B_N + r]] += coefs[m] * 0.125f;
}

// ================= fallback: proven round-1 fp32 path =================

#define TM 128
#define TN 128
#define TK 32
#define CT 8

__global__ __launch_bounds__(256) void ve_zero_out(float* __restrict__ out, int n4) {
    int i = blockIdx.x * blockDim.x + threadIdx.x;
    const float4 z = make_float4(0.f, 0.f, 0.f, 0.f);
    for (; i < n4; i += gridDim.x * blockDim.x)
        reinterpret_cast<float4*>(out)[i] = z;
}

__global__ __launch_bounds__(256) void ve_gemm_argmax_fb(
        const float* __restrict__ x, const float* __restrict__ W,
        const float* __restrict__ bias, float2* __restrict__ part) {
    __shared__ float xs[TK][TM + 1];
    __shared__ float ws[TK][TN];
    const int ct = blockIdx.x, rt = blockIdx.y, m = blockIdx.z;
    const int tid = threadIdx.x;
    const int tx = tid & 15, ty = tid >> 4;
    const int r0 = rt * TM, c0 = ct * TN;
    float acc[8][8];
#pragma unroll
    for (int i = 0; i < 8; i++)
#pragma unroll
        for (int j = 0; j < 8; j++) acc[i][j] = 0.f;
    const float* xbase = x + (size_t)r0 * D_K;
    for (int kt = 0; kt < D_K; kt += TK) {
#pragma unroll
        for (int i = 0; i < 4; i++) {
            int li = tid + i * 256;
            int row = li >> 3, kq = li & 7;
            float4 v = *reinterpret_cast<const float4*>(xbase + (size_t)row * D_K + kt + kq * 4);
            int kk = kq * 4;
            xs[kk + 0][row] = v.x; xs[kk + 1][row] = v.y;
            xs[kk + 2][row] = v.z; xs[kk + 3][row] = v.w;
        }
#pragma unroll
        for (int i = 0; i < 4; i++) {
            int li = tid + i * 256;
            int kk = li >> 5, cq = li & 31;
            int c = c0 + cq * 4;
            const float* p = W + ((size_t)(m * D_K + kt + kk)) * C_N + c;
            float4 v;
            if (c + 3 < C_N) v = *reinterpret_cast<const float4*>(p);
            else {
                v.x = (c + 0 < C_N) ? p[0] : 0.f; v.y = (c + 1 < C_N) ? p[1] : 0.f;
                v.z = (c + 2 < C_N) ? p[2] : 0.f; v.w = (c + 3 < C_N) ? p[3] : 0.f;
            }
            ws[kk][cq * 4 + 0] = v.x; ws[kk][cq * 4 + 1] = v.y;
            ws[kk][cq * 4 + 2] = v.z; ws[kk][cq * 4 + 3] = v.w;
        }
        __syncthreads();
        for (int kk = 0; kk < TK; kk++) {
            float a[8], bb[8];
#pragma unroll
            for (int i = 0; i < 8; i++) a[i] = xs[kk][ty + i * 16];
#pragma unroll
            for (int j = 0; j < 8; j++) bb[j] = ws[kk][tx + j * 16];
#pragma unroll
            for (int i = 0; i < 8; i++)
#pragma unroll
                for (int j = 0; j < 8; j++) acc[i][j] += a[i] * bb[j];
        }
        __syncthreads();
    }
    const float NEG_INF = -__builtin_huge_valf();
    float bv[8]; int cv[8];
#pragma unroll
    for (int j = 0; j < 8; j++) {
        int c = c0 + tx + j * 16;
        cv[j] = c;
        bv[j] = (c < C_N) ? bias[m * C_N + c] : 0.f;
    }
#pragma unroll
    for (int i = 0; i < 8; i++) {
        int r = r0 + ty + i * 16;
        float best = NEG_INF; int bidx = 0x7fffffff;
#pragma unroll
        for (int j = 0; j < 8; j++) {
            int c = cv[j];
            float v = (c < C_N) ? (acc[i][j] + bv[j]) : NEG_INF;
            if (v > best || (v == best && c < bidx)) { best = v; bidx = c; }
        }
#pragma unroll
        for (int mask = 1; mask < 16; mask <<= 1) {
            float ov = __shfl_xor(best, mask);
            int oi = __shfl_xor(bidx, mask);
            if (ov > best || (ov == best && oi < bidx)) { best = ov; bidx = oi; }
        }
        if (tx == 0) part[((size_t)m * B_N + r) * CT + ct] = make_float2(best, __int_as_float(bidx));
    }
}

__global__ __launch_bounds__(256) void ve_vote_fb(const float2* __restrict__ part,
        const float* __restrict__ coefs, float* __restrict__ out) {
    int r = blockIdx.x * blockDim.x + threadIdx.x;
    if (r >= B_N) return;
    const float NEG_INF = -__builtin_huge_valf();
#pragma unroll
    for (int m = 0; m < M_N; m++) {
        float best = NEG_INF; int bidx = 0x7fffffff;
#pragma unroll
        for (int ctt = 0; ctt < CT; ctt++) {
            float2 p = part[((size_t)m * B_N + r) * CT + ctt];
            int oi = __float_as_int(p.y);
            if (p.x > best || (p.x == best && oi < bidx)) { best = p.x; bidx = oi; }
        }
        out[(size_t)r * C_N + bidx] += coefs[m] * 0.125f;
    }
}

// ================= launcher =================

extern "C" void kernel_launch(void* const* d_in, const int* in_sizes, int n_in,
                              void* d_out, int out_size, void* d_ws, size_t ws_size,
                              hipStream_t stream) {
    const float* x     = (const float*)d_in[0];
    const float* W     = (const float*)d_in[1];
    const float* bias  = (const float*)d_in[2];
    const float* coefs = (const float*)d_in[3];
    float* out = (float*)d_out;

    const size_t NEED = (57ull << 20) + 4096;
    if (ws_size >= NEED) {
        char* ws = (char*)d_ws;
        unsigned short* Xf    = (unsigned short*)(ws);                   // 16 MiB
        unsigned short* WT16  = (unsigned short*)(ws + (16ull << 20));   //  8 MiB
        float4*         part  = (float4*)(ws + (24ull << 20));           //  2 MiB
        float2*         part2 = (float2*)(ws + (32ull << 20));           //  8 MiB
        unsigned int*   wout  = (unsigned int*)(ws + (40ull << 20));     // 512 KiB
        unsigned int*   rlist = (unsigned int*)(ws + (40ull << 20) + (512ull << 10)); // 512 KiB
        unsigned int*   cnts  = (unsigned int*)(ws + (41ull << 20));     // 32 B

        ve_conv_x16<<<8192, 256, 0, stream>>>(x, Xf, cnts);
        ve_conv_w16<<<dim3(16, 8, 8), 256, 0, stream>>>(W, WT16);
        ve_gemm16c<<<dim3(128, 1, 8), 256, 0, stream>>>(Xf, WT16, bias, part);
        ve_flagS<<<64, 256, 0, stream>>>(part, wout, rlist, cnts);
        ve_exact_g<<<dim3(8, 16, 8), 256, 0, stream>>>(x, W, bias, rlist, cnts, part2);
        ve_merge_x<<<512, 256, 0, stream>>>(part2, rlist, cnts, wout);
        ve_votef<<<64, 256, 0, stream>>>(wout, coefs, out);
    } else {
        float2* partf = (float2*)d_ws;
        ve_zero_out<<<2048, 256, 0, stream>>>(out, B_N * C_N / 4);
        dim3 grid(CT, B_N / TM, M_N);
        ve_gemm_argmax_fb<<<grid, 256, 0, stream>>>(x, W, bias, partf);
        ve_vote_fb<<<(B_N + 255) / 256, 256, 0, stream>>>(partf, coefs, out);
    }
}